// Round 10
// baseline (68.139 us; speedup 1.0000x reference)
//
#include <hip/hip_runtime.h>
#include <hip/hip_bf16.h>

typedef __bf16 bf16x8 __attribute__((ext_vector_type(8)));
typedef float  f32x4  __attribute__((ext_vector_type(4)));

#define NFEAT 128
#define NSAMP 8192
#define MT 8          // 8 M-tiles of 16 samples = 128 samples per wave

// Fragment layout (mfma_f32_16x16x32_bf16), verified rounds 1-9:
//   A: lane l holds A[row = l&15][kslot = 8*(l>>4) + j], j = 0..7
//   B: lane l holds B[kslot = 8*(l>>4) + j][col = l&15]
//   D: lane l reg r holds D[row = 4*(l>>4) + r][col = l&15]
// K-permutation pi(ks,g,j) = 32*ks + 16*(j>>2) + 4*g + (j&3) lets D-layout
// values (row = 16*mt + 4*g + r) feed the next layer's B-fragment in-lane.
//
// R8 measured: VGPR=136 (8 over the 128 residency cliff, m69), VALUBusy 40%,
// MfmaUtil 13.5%, Occupancy 10.8% -> latency-bound at 2 waves/SIMD.
// R10 = EXACT R4 body (best known, 33.1us) + launch_bounds(256,4) to force
// <=128 VGPR + per-iter store (kills the acc[8] live range to give the
// allocator the 8-reg slack). Single-variable experiment on the cliff.
// ---------------------------------------------------------------------------
__global__ __launch_bounds__(256, 4) void nam_main(
    const float* __restrict__ X,  const float* __restrict__ W0,
    const float* __restrict__ b0, const float* __restrict__ W1,
    const float* __restrict__ b1, const float* __restrict__ W2,
    const float* __restrict__ b2, const float* __restrict__ W3,
    const float* __restrict__ b3, float* __restrict__ part) {
  const int tid = threadIdx.x;
  const int l  = tid & 63;               // lane in wave
  const int w  = tid >> 6;               // wave 0..3
  const int lg = l >> 4, ls = l & 15;
  const int f  = blockIdx.x >> 4;        // one feature per block
  const int cg = blockIdx.x & 15;        // chunk group
  const int n0 = (cg * 4 + w) * 128;     // this wave's 128 samples

  __shared__ __align__(16) __bf16 w1s[8][64][8];   // 8 KiB
  __shared__ __align__(16) __bf16 w2s[4][64][8];   // 4 KiB

  // ---- per-lane layer-1 weights (pi-indexed) + bias/head fragments ----
  float w0p[16], b0p[16];
#pragma unroll
  for (int ks = 0; ks < 2; ++ks)
#pragma unroll
    for (int j = 0; j < 8; ++j) {
      int kp = 32 * ks + 16 * (j >> 2) + 4 * lg + (j & 3);
      w0p[ks * 8 + j] = W0[f * 64 + kp];
      b0p[ks * 8 + j] = b0[f * 64 + kp];
    }
  f32x4 b1f[4], b2f[2], w3f[2];
#pragma unroll
  for (int mt = 0; mt < 4; ++mt)
    b1f[mt] = *(const f32x4*)(b1 + f * 64 + 16 * mt + 4 * lg);
#pragma unroll
  for (int mt = 0; mt < 2; ++mt)
    b2f[mt] = *(const f32x4*)(b2 + f * 32 + 16 * mt + 4 * lg);
#pragma unroll
  for (int mt = 0; mt < 2; ++mt)
    w3f[mt] = *(const f32x4*)(W3 + f * 32 + 16 * mt + 4 * lg);
  const float b3v = b3[f];

  // ---- cooperative fragment build: 768 slots over 256 threads ----
#pragma unroll
  for (int i = 0; i < 3; ++i) {
    int s = tid + 256 * i;
    int arr = (s >= 512);
    int s0 = arr ? s - 512 : s;
    int sl = s0 & 63, q = s0 >> 6;
    int slg = sl >> 4, sls = sl & 15, mt = q >> 1, ks = q & 1;
    const float* base = arr ? (W2 + f * 2048 + 16 * mt + sls)
                            : (W1 + f * 4096 + 16 * mt + sls);
    int stride = arr ? 32 : 64;
    bf16x8 v;
#pragma unroll
    for (int j = 0; j < 8; ++j) {
      int ii = 32 * ks + 16 * (j >> 2) + 4 * slg + (j & 3);
      v[j] = (__bf16)base[ii * stride];
    }
    if (arr) *(bf16x8*)&w2s[q][sl][0] = v;
    else     *(bf16x8*)&w1s[q][sl][0] = v;
  }
  __syncthreads();

  // ---- fragments to registers (conflict-free ds_read_b128) ----
  bf16x8 w1f[8], w2f[4];
#pragma unroll
  for (int q = 0; q < 8; ++q) w1f[q] = *(const bf16x8*)&w1s[q][l][0];
#pragma unroll
  for (int q = 0; q < 4; ++q) w2f[q] = *(const bf16x8*)&w2s[q][l][0];

  const float* xb = X + (size_t)n0 * NFEAT + f;
  float* pout = part + (size_t)f * NSAMP + n0;

#pragma unroll
  for (int m = 0; m < MT; ++m) {
    const float xv = xb[(16 * m + ls) * NFEAT];   // 16-lane broadcast gather
    // ---- layer 1 in VALU: a1[ks][j] = relu(w0[pi]*x + b0[pi]) ----
    bf16x8 a1[2];
#pragma unroll
    for (int ks = 0; ks < 2; ++ks)
#pragma unroll
      for (int j = 0; j < 8; ++j) {
        float h = fmaf(xv, w0p[ks * 8 + j], b0p[ks * 8 + j]);
        a1[ks][j] = (__bf16)fmaxf(h, 0.f);
      }
    // ---- layer 2: D[out2][sample], C-init = b1 ----
    f32x4 h2[4];
#pragma unroll
    for (int mt = 0; mt < 4; ++mt) {
      f32x4 c = b1f[mt];
      c = __builtin_amdgcn_mfma_f32_16x16x32_bf16(w1f[mt * 2 + 0], a1[0], c, 0, 0, 0);
      c = __builtin_amdgcn_mfma_f32_16x16x32_bf16(w1f[mt * 2 + 1], a1[1], c, 0, 0, 0);
      h2[mt] = c;
    }
    // ---- relu + pack: h2 -> L3 B-fragments (pi K) ----
    bf16x8 bfr[2];
#pragma unroll
    for (int ks = 0; ks < 2; ++ks)
#pragma unroll
      for (int j = 0; j < 8; ++j) {
        float v = h2[2 * ks + (j >> 2)][j & 3];
        bfr[ks][j] = (__bf16)fmaxf(v, 0.f);
      }
    // ---- layer 3: D[out3][sample], C-init = b2 ----
    f32x4 h3[2];
#pragma unroll
    for (int mt = 0; mt < 2; ++mt) {
      f32x4 c = b2f[mt];
      c = __builtin_amdgcn_mfma_f32_16x16x32_bf16(w2f[mt * 2 + 0], bfr[0], c, 0, 0, 0);
      c = __builtin_amdgcn_mfma_f32_16x16x32_bf16(w2f[mt * 2 + 1], bfr[1], c, 0, 0, 0);
      h3[mt] = c;
    }
    // ---- epilogue: relu, dot with w3, reduce across lane-groups, store ----
    float p0 = (lg == 0) ? b3v : 0.f, p1 = 0.f;
#pragma unroll
    for (int r = 0; r < 4; ++r) {
      p0 = fmaf(fmaxf(h3[0][r], 0.f), w3f[0][r], p0);
      p1 = fmaf(fmaxf(h3[1][r], 0.f), w3f[1][r], p1);
    }
    float v = p0 + p1;
    v += __shfl_xor(v, 16, 64);
    v += __shfl_xor(v, 32, 64);
    if (l < 16) pout[16 * m + l] = v;
  }
}

// ---------------------------------------------------------------------------
// Reduce: out[n] = bias + sum_f part[f][n]. Fixed order -> deterministic.
// ---------------------------------------------------------------------------
__global__ __launch_bounds__(256) void nam_reduce(const float* __restrict__ part,
                                                  const float* __restrict__ bias,
                                                  float* __restrict__ out) {
  int tid = threadIdx.x;
  int quad = blockIdx.x * 64 + (tid & 63);
  int gs = tid >> 6;
  f32x4 s = {0.f, 0.f, 0.f, 0.f};
#pragma unroll
  for (int g = gs * 32; g < gs * 32 + 32; ++g)
    s += *(const f32x4*)(part + (size_t)g * NSAMP + quad * 4);
  __shared__ f32x4 red[256];
  red[tid] = s;
  __syncthreads();
  if (gs == 0) {
    f32x4 t = red[tid] + red[tid + 64] + red[tid + 128] + red[tid + 192];
    float bv = bias[0];
    t[0] += bv; t[1] += bv; t[2] += bv; t[3] += bv;
    *(f32x4*)(out + quad * 4) = t;
  }
}

// ---------------------------------------------------------------------------
// Fallback (only if ws too small): naive fp32, correct but slow.
// ---------------------------------------------------------------------------
__global__ void nam_naive(const float* __restrict__ X, const float* __restrict__ W0,
                          const float* __restrict__ b0, const float* __restrict__ W1,
                          const float* __restrict__ b1, const float* __restrict__ W2,
                          const float* __restrict__ b2, const float* __restrict__ W3,
                          const float* __restrict__ b3, const float* __restrict__ bias,
                          float* __restrict__ out) {
  int n = blockIdx.x * 64 + threadIdx.x;
  if (n >= NSAMP) return;
  float s = bias[0];
  for (int f = 0; f < NFEAT; ++f) {
    float xv = X[n * NFEAT + f];
    float h1[64], h2[64];
    for (int i = 0; i < 64; ++i)
      h1[i] = fmaxf(fmaf(xv, W0[f * 64 + i], b0[f * 64 + i]), 0.f);
    for (int k = 0; k < 64; ++k) {
      float t = b1[f * 64 + k];
      for (int i = 0; i < 64; ++i) t = fmaf(h1[i], W1[f * 4096 + i * 64 + k], t);
      h2[k] = fmaxf(t, 0.f);
    }
    float c = b3[f];
    for (int k = 0; k < 32; ++k) {
      float t = b2[f * 32 + k];
      for (int i = 0; i < 64; ++i) t = fmaf(h2[i], W2[f * 2048 + i * 32 + k], t);
      c = fmaf(fmaxf(t, 0.f), W3[f * 32 + k], c);
    }
    s += c;
  }
  out[n] = s;
}

extern "C" void kernel_launch(void* const* d_in, const int* in_sizes, int n_in,
                              void* d_out, int out_size, void* d_ws, size_t ws_size,
                              hipStream_t stream) {
  const float* X    = (const float*)d_in[0];
  const float* W0   = (const float*)d_in[1];
  const float* b0   = (const float*)d_in[2];
  const float* W1   = (const float*)d_in[3];
  const float* b1   = (const float*)d_in[4];
  const float* W2   = (const float*)d_in[5];
  const float* b2   = (const float*)d_in[6];
  const float* W3   = (const float*)d_in[7];
  const float* b3   = (const float*)d_in[8];
  const float* bias = (const float*)d_in[9];
  float* out = (float*)d_out;

  const size_t PART_BYTES = (size_t)NFEAT * NSAMP * 4;    // 4 MiB
  if (ws_size < PART_BYTES) {
    nam_naive<<<NSAMP / 64, 64, 0, stream>>>(X, W0, b0, W1, b1, W2, b2, W3, b3, bias, out);
    return;
  }
  float* partb = (float*)d_ws;

  nam_main<<<NFEAT * 16, 256, 0, stream>>>(X, W0, b0, W1, b1, W2, b2, W3, b3, partb);
  nam_reduce<<<(NSAMP / 4) / 64, 256, 0, stream>>>(partb, bias, out);
}

// Round 11
// 34.165 us; speedup vs baseline: 1.9944x; 1.9944x over previous
//
#include <hip/hip_runtime.h>
#include <hip/hip_bf16.h>

typedef __bf16 bf16x8 __attribute__((ext_vector_type(8)));
typedef float  f32x4  __attribute__((ext_vector_type(4)));

#define NFEAT 128
#define NSAMP 8192
#define MT 16         // 16 M-tiles of 16 samples = 256 samples per wave

// Fragment layout (mfma_f32_16x16x32_bf16), verified rounds 1-10:
//   A: lane l holds A[row = l&15][kslot = 8*(l>>4) + j], j = 0..7
//   B: lane l holds B[kslot = 8*(l>>4) + j][col = l&15]
//   D: lane l reg r holds D[row = 4*(l>>4) + r][col = l&15]
// K-permutation pi(ks,g,j) = 32*ks + 16*(j>>2) + 4*g + (j&3) lets D-layout
// values (row = 16*mt + 4*g + r) feed the next layer's B-fragment in-lane.
//
// Evidence to date: R4 body (VALU L1 + full unroll) is the best structure
// (33.1us); unroll-1 regresses (37.9) -> cross-iter ILP matters; forced VGPR
// caps cause catastrophic spills (R10: VGPR=64, 62MB scratch writes, 70us);
// OccupancyPercent counter is unreliable (fillBuffer @85% HBM reports 8.5%).
// R11: amortize setup 2x (MT=16, 1024 blocks), per-iter store keeps live
// state flat across the 16-deep unroll. Inner body untouched.
// ---------------------------------------------------------------------------
__global__ __launch_bounds__(256) void nam_main(
    const float* __restrict__ X,  const float* __restrict__ W0,
    const float* __restrict__ b0, const float* __restrict__ W1,
    const float* __restrict__ b1, const float* __restrict__ W2,
    const float* __restrict__ b2, const float* __restrict__ W3,
    const float* __restrict__ b3, float* __restrict__ part) {
  const int tid = threadIdx.x;
  const int l  = tid & 63;               // lane in wave
  const int w  = tid >> 6;               // wave 0..3
  const int lg = l >> 4, ls = l & 15;
  const int f  = blockIdx.x >> 3;        // one feature per block
  const int cg = blockIdx.x & 7;         // chunk group
  const int n0 = (cg * 4 + w) * 256;     // this wave's 256 samples

  __shared__ __align__(16) __bf16 w1s[8][64][8];   // 8 KiB
  __shared__ __align__(16) __bf16 w2s[4][64][8];   // 4 KiB

  // ---- per-lane layer-1 weights (pi-indexed, f32x4 loads; R6-verified) ----
  f32x4 w0v[4], b0v[4];
#pragma unroll
  for (int ks = 0; ks < 2; ++ks)
#pragma unroll
    for (int h = 0; h < 2; ++h) {
      w0v[ks * 2 + h] = *(const f32x4*)(W0 + f * 64 + 32 * ks + 16 * h + 4 * lg);
      b0v[ks * 2 + h] = *(const f32x4*)(b0 + f * 64 + 32 * ks + 16 * h + 4 * lg);
    }
  f32x4 b1f[4], b2f[2], w3f[2];
#pragma unroll
  for (int mt = 0; mt < 4; ++mt)
    b1f[mt] = *(const f32x4*)(b1 + f * 64 + 16 * mt + 4 * lg);
#pragma unroll
  for (int mt = 0; mt < 2; ++mt)
    b2f[mt] = *(const f32x4*)(b2 + f * 32 + 16 * mt + 4 * lg);
#pragma unroll
  for (int mt = 0; mt < 2; ++mt)
    w3f[mt] = *(const f32x4*)(W3 + f * 32 + 16 * mt + 4 * lg);
  const float b3v = b3[f];

  // ---- cooperative fragment build: 768 slots over 256 threads ----
#pragma unroll
  for (int i = 0; i < 3; ++i) {
    int s = tid + 256 * i;
    int arr = (s >= 512);
    int s0 = arr ? s - 512 : s;
    int sl = s0 & 63, q = s0 >> 6;
    int slg = sl >> 4, sls = sl & 15, mt = q >> 1, ks = q & 1;
    const float* base = arr ? (W2 + f * 2048 + 16 * mt + sls)
                            : (W1 + f * 4096 + 16 * mt + sls);
    int stride = arr ? 32 : 64;
    bf16x8 v;
#pragma unroll
    for (int j = 0; j < 8; ++j) {
      int ii = 32 * ks + 16 * (j >> 2) + 4 * slg + (j & 3);
      v[j] = (__bf16)base[ii * stride];
    }
    if (arr) *(bf16x8*)&w2s[q][sl][0] = v;
    else     *(bf16x8*)&w1s[q][sl][0] = v;
  }
  __syncthreads();

  // ---- fragments to registers (conflict-free ds_read_b128) ----
  bf16x8 w1f[8], w2f[4];
#pragma unroll
  for (int q = 0; q < 8; ++q) w1f[q] = *(const bf16x8*)&w1s[q][l][0];
#pragma unroll
  for (int q = 0; q < 4; ++q) w2f[q] = *(const bf16x8*)&w2s[q][l][0];

  const float* xb = X + (size_t)n0 * NFEAT + f;
  float* pout = part + (size_t)f * NSAMP + n0;

#pragma unroll
  for (int m = 0; m < MT; ++m) {
    const float xv = xb[(16 * m + ls) * NFEAT];   // 16-lane broadcast gather
    // ---- layer 1 in VALU: a1[ks][j] = relu(w0[pi]*x + b0[pi]) ----
    bf16x8 a1[2];
#pragma unroll
    for (int ks = 0; ks < 2; ++ks)
#pragma unroll
      for (int j = 0; j < 8; ++j) {
        float h = fmaf(xv, w0v[ks * 2 + (j >> 2)][j & 3],
                       b0v[ks * 2 + (j >> 2)][j & 3]);
        a1[ks][j] = (__bf16)fmaxf(h, 0.f);
      }
    // ---- layer 2: D[out2][sample], C-init = b1 ----
    f32x4 h2[4];
#pragma unroll
    for (int mt = 0; mt < 4; ++mt) {
      f32x4 c = b1f[mt];
      c = __builtin_amdgcn_mfma_f32_16x16x32_bf16(w1f[mt * 2 + 0], a1[0], c, 0, 0, 0);
      c = __builtin_amdgcn_mfma_f32_16x16x32_bf16(w1f[mt * 2 + 1], a1[1], c, 0, 0, 0);
      h2[mt] = c;
    }
    // ---- relu + pack: h2 -> L3 B-fragments (pi K) ----
    bf16x8 bfr[2];
#pragma unroll
    for (int ks = 0; ks < 2; ++ks)
#pragma unroll
      for (int j = 0; j < 8; ++j) {
        float v = h2[2 * ks + (j >> 2)][j & 3];
        bfr[ks][j] = (__bf16)fmaxf(v, 0.f);
      }
    // ---- layer 3: D[out3][sample], C-init = b2 ----
    f32x4 h3[2];
#pragma unroll
    for (int mt = 0; mt < 2; ++mt) {
      f32x4 c = b2f[mt];
      c = __builtin_amdgcn_mfma_f32_16x16x32_bf16(w2f[mt * 2 + 0], bfr[0], c, 0, 0, 0);
      c = __builtin_amdgcn_mfma_f32_16x16x32_bf16(w2f[mt * 2 + 1], bfr[1], c, 0, 0, 0);
      h3[mt] = c;
    }
    // ---- epilogue: relu, dot with w3, reduce across lane-groups, store ----
    float p0 = (lg == 0) ? b3v : 0.f, p1 = 0.f;
#pragma unroll
    for (int r = 0; r < 4; ++r) {
      p0 = fmaf(fmaxf(h3[0][r], 0.f), w3f[0][r], p0);
      p1 = fmaf(fmaxf(h3[1][r], 0.f), w3f[1][r], p1);
    }
    float v = p0 + p1;
    v += __shfl_xor(v, 16, 64);
    v += __shfl_xor(v, 32, 64);
    if (l < 16) pout[16 * m + l] = v;
  }
}

// ---------------------------------------------------------------------------
// Reduce: out[n] = bias + sum_f part[f][n]. Fixed order -> deterministic.
// ---------------------------------------------------------------------------
__global__ __launch_bounds__(256) void nam_reduce(const float* __restrict__ part,
                                                  const float* __restrict__ bias,
                                                  float* __restrict__ out) {
  int tid = threadIdx.x;
  int quad = blockIdx.x * 64 + (tid & 63);
  int gs = tid >> 6;
  f32x4 s = {0.f, 0.f, 0.f, 0.f};
#pragma unroll
  for (int g = gs * 32; g < gs * 32 + 32; ++g)
    s += *(const f32x4*)(part + (size_t)g * NSAMP + quad * 4);
  __shared__ f32x4 red[256];
  red[tid] = s;
  __syncthreads();
  if (gs == 0) {
    f32x4 t = red[tid] + red[tid + 64] + red[tid + 128] + red[tid + 192];
    float bv = bias[0];
    t[0] += bv; t[1] += bv; t[2] += bv; t[3] += bv;
    *(f32x4*)(out + quad * 4) = t;
  }
}

// ---------------------------------------------------------------------------
// Fallback (only if ws too small): naive fp32, correct but slow.
// ---------------------------------------------------------------------------
__global__ void nam_naive(const float* __restrict__ X, const float* __restrict__ W0,
                          const float* __restrict__ b0, const float* __restrict__ W1,
                          const float* __restrict__ b1, const float* __restrict__ W2,
                          const float* __restrict__ b2, const float* __restrict__ W3,
                          const float* __restrict__ b3, const float* __restrict__ bias,
                          float* __restrict__ out) {
  int n = blockIdx.x * 64 + threadIdx.x;
  if (n >= NSAMP) return;
  float s = bias[0];
  for (int f = 0; f < NFEAT; ++f) {
    float xv = X[n * NFEAT + f];
    float h1[64], h2[64];
    for (int i = 0; i < 64; ++i)
      h1[i] = fmaxf(fmaf(xv, W0[f * 64 + i], b0[f * 64 + i]), 0.f);
    for (int k = 0; k < 64; ++k) {
      float t = b1[f * 64 + k];
      for (int i = 0; i < 64; ++i) t = fmaf(h1[i], W1[f * 4096 + i * 64 + k], t);
      h2[k] = fmaxf(t, 0.f);
    }
    float c = b3[f];
    for (int k = 0; k < 32; ++k) {
      float t = b2[f * 32 + k];
      for (int i = 0; i < 64; ++i) t = fmaf(h2[i], W2[f * 2048 + i * 32 + k], t);
      c = fmaf(fmaxf(t, 0.f), W3[f * 32 + k], c);
    }
    s += c;
  }
  out[n] = s;
}

extern "C" void kernel_launch(void* const* d_in, const int* in_sizes, int n_in,
                              void* d_out, int out_size, void* d_ws, size_t ws_size,
                              hipStream_t stream) {
  const float* X    = (const float*)d_in[0];
  const float* W0   = (const float*)d_in[1];
  const float* b0   = (const float*)d_in[2];
  const float* W1   = (const float*)d_in[3];
  const float* b1   = (const float*)d_in[4];
  const float* W2   = (const float*)d_in[5];
  const float* b2   = (const float*)d_in[6];
  const float* W3   = (const float*)d_in[7];
  const float* b3   = (const float*)d_in[8];
  const float* bias = (const float*)d_in[9];
  float* out = (float*)d_out;

  const size_t PART_BYTES = (size_t)NFEAT * NSAMP * 4;    // 4 MiB
  if (ws_size < PART_BYTES) {
    nam_naive<<<NSAMP / 64, 64, 0, stream>>>(X, W0, b0, W1, b1, W2, b2, W3, b3, bias, out);
    return;
  }
  float* partb = (float*)d_ws;

  nam_main<<<NFEAT * 8, 256, 0, stream>>>(X, W0, b0, W1, b1, W2, b2, W3, b3, partb);
  nam_reduce<<<(NSAMP / 4) / 64, 256, 0, stream>>>(partb, bias, out);
}